// Round 5
// baseline (651.034 us; speedup 1.0000x reference)
//
#include <hip/hip_runtime.h>
#include <hip/hip_bf16.h>
#include <cstdint>

#define NEG (-1.0e30f)
#define INVLN2 1.44269504088896340736f
#define LN2    0.69314718055994530942f

typedef unsigned short u16;
typedef __attribute__((ext_vector_type(8))) short short8;
typedef __attribute__((ext_vector_type(4))) float f32x4;

typedef const __attribute__((address_space(1))) void cg_void;
typedef __attribute__((address_space(3))) void lds_void;

// dims
#define Bsz   32
#define Tlen  1000
#define Cdim  512
#define Vdim  2000
#define Udim  100
#define Mrows (Bsz * Tlen)   // 32000
#define Npad  2048
#define GROW  128            // padded G row (floats): 0..99 labels, 100 blank, pad

// ws layout (bytes). G (16.4 MB) aliases a_bf (32.8 MB): a_bf dead after gemm.
#define WS_ABF 0u
#define WS_G   0u
#define WS_WBF 32768000u                    // a_bf: 32000*512*2
#define WS_Z   (WS_WBF + 2097152u)          // w_bf: 2048*512*2
#define WS_ACC (WS_Z + 128000000u)          // Z: 32000*2000*2; then accum: 2 floats

__device__ inline u16 f2bf(float x) {
  uint32_t u = __float_as_uint(x);
  uint32_t r = (u + 0x7fffu + ((u >> 16) & 1u)) >> 16;
  return (u16)r;
}
__device__ inline float bf2f(u16 u) {
  return __uint_as_float(((uint32_t)u) << 16);
}

__device__ inline float waveMax(float v) {
  #pragma unroll
  for (int o = 32; o > 0; o >>= 1) v = fmaxf(v, __shfl_down(v, o));
  return v;
}
__device__ inline float waveSum(float v) {
  #pragma unroll
  for (int o = 32; o > 0; o >>= 1) v += __shfl_down(v, o);
  return v;
}

// log-sum-exp in log2 space (native v_exp_f32 / v_log_f32)
__device__ inline float lse2_2(float a, float b) {
  float m = fmaxf(a, b);
  return m + log2f(exp2f(a - m) + exp2f(b - m));
}
__device__ inline float lse3_2(float a, float b, float c) {
  float m = fmaxf(a, fmaxf(b, c));
  return m + log2f(exp2f(a - m) + exp2f(b - m) + exp2f(c - m));
}

// shift value from lane-1 into this lane via DPP wave_shr:1 (VALU, no LDS).
__device__ inline float shiftup1(float x, float fill) {
  int r = __builtin_amdgcn_update_dpp(__float_as_int(fill), __float_as_int(x),
                                      0x138, 0xF, 0xF, false);
  return __int_as_float(r);
}

// ---------------- K1: fp32 -> bf16 conversion, vectorized ------------------
__global__ void convert_kernel(const float4* __restrict__ enc4, const float4* __restrict__ W4,
                               uint4* __restrict__ a4, uint4* __restrict__ w4,
                               float* __restrict__ accum) {
  int idx = blockIdx.x * blockDim.x + threadIdx.x;
  int stride = gridDim.x * blockDim.x;
  if (idx == 0) { accum[0] = 0.0f; accum[1] = 0.0f; }
  const int nA = Mrows * Cdim / 8;
  const int nW = Vdim * Cdim / 8;
  const int nWp = Npad * Cdim / 8;
  for (int i = idx; i < nA; i += stride) {
    float4 x = enc4[2 * i], y = enc4[2 * i + 1];
    uint4 o;
    o.x = (uint32_t)f2bf(x.x) | ((uint32_t)f2bf(x.y) << 16);
    o.y = (uint32_t)f2bf(x.z) | ((uint32_t)f2bf(x.w) << 16);
    o.z = (uint32_t)f2bf(y.x) | ((uint32_t)f2bf(y.y) << 16);
    o.w = (uint32_t)f2bf(y.z) | ((uint32_t)f2bf(y.w) << 16);
    a4[i] = o;
  }
  for (int i = idx; i < nWp; i += stride) {
    uint4 o = {0, 0, 0, 0};
    if (i < nW) {
      float4 x = W4[2 * i], y = W4[2 * i + 1];
      o.x = (uint32_t)f2bf(x.x) | ((uint32_t)f2bf(x.y) << 16);
      o.y = (uint32_t)f2bf(x.z) | ((uint32_t)f2bf(x.w) << 16);
      o.z = (uint32_t)f2bf(y.x) | ((uint32_t)f2bf(y.y) << 16);
      o.w = (uint32_t)f2bf(y.z) | ((uint32_t)f2bf(y.w) << 16);
    }
    w4[i] = o;
  }
}

// ---------------- K2: bf16 GEMM (A: 32000x512, W: 2048x512, C = A*W^T) -----
__global__ __launch_bounds__(256) void gemm_kernel(const u16* __restrict__ A,
                                                   const u16* __restrict__ Wb,
                                                   u16* __restrict__ Z) {
  __shared__ __attribute__((aligned(16))) u16 As[128 * 64];
  __shared__ __attribute__((aligned(16))) u16 Bs[128 * 64];
  const int tid = threadIdx.x;
  const int wave = tid >> 6;
  const int lane = tid & 63;
  const int nBase = blockIdx.x * 128;
  const int mBase = blockIdx.y * 128;
  const int m_lane = lane & 15;
  const int quad = lane >> 4;

  f32x4 acc[4][4];
  const f32x4 zero4 = {0.0f, 0.0f, 0.0f, 0.0f};
  #pragma unroll
  for (int i = 0; i < 4; ++i)
    #pragma unroll
    for (int j = 0; j < 4; ++j) acc[i][j] = zero4;

  for (int k0 = 0; k0 < Cdim; k0 += 64) {
    #pragma unroll
    for (int r = 0; r < 4; ++r) {
      int u = r * 256 + tid;
      int g = u >> 3;
      int q = (u & 7) ^ (g & 7);
      const u16* gpA = A + ((size_t)(mBase + g) << 9) + (k0 + (q << 3));
      __builtin_amdgcn_global_load_lds((cg_void*)gpA, (lds_void*)&As[(r * 4 + wave) * 512],
                                       16, 0, 0);
      const u16* gpB = Wb + ((size_t)(nBase + g) << 9) + (k0 + (q << 3));
      __builtin_amdgcn_global_load_lds((cg_void*)gpB, (lds_void*)&Bs[(r * 4 + wave) * 512],
                                       16, 0, 0);
    }
    __syncthreads();
    #pragma unroll
    for (int kk = 0; kk < 2; ++kk) {
      short8 af[4], bfv[4];
      #pragma unroll
      for (int mi = 0; mi < 4; ++mi) {
        int row = (wave >> 1) * 64 + mi * 16 + m_lane;
        int q = (kk * 4 + quad) ^ (row & 7);
        af[mi] = *(const short8*)&As[row * 64 + (q << 3)];
      }
      #pragma unroll
      for (int ni = 0; ni < 4; ++ni) {
        int col = (wave & 1) * 64 + ni * 16 + m_lane;
        int q = (kk * 4 + quad) ^ (col & 7);
        bfv[ni] = *(const short8*)&Bs[col * 64 + (q << 3)];
      }
      #pragma unroll
      for (int mi = 0; mi < 4; ++mi)
        #pragma unroll
        for (int ni = 0; ni < 4; ++ni)
          acc[mi][ni] = __builtin_amdgcn_mfma_f32_16x16x32_bf16(af[mi], bfv[ni],
                                                                acc[mi][ni], 0, 0, 0);
    }
    __syncthreads();
  }
  #pragma unroll
  for (int ni = 0; ni < 4; ++ni) {
    int col = nBase + (wave & 1) * 64 + ni * 16 + m_lane;
    if (col < Vdim) {
      #pragma unroll
      for (int mi = 0; mi < 4; ++mi) {
        int row0 = mBase + (wave >> 1) * 64 + mi * 16 + quad * 4;
        #pragma unroll
        for (int rg = 0; rg < 4; ++rg)
          Z[(size_t)(row0 + rg) * Vdim + col] = f2bf(acc[mi][ni][rg]);
      }
    }
  }
}

// ---------------- K3: fused softmax stats + CR loss + CTC gather -----------
__global__ __launch_bounds__(256) void cr_stats_kernel(const u16* __restrict__ Z,
                                                       const float* __restrict__ bias,
                                                       const int* __restrict__ lens,
                                                       const int* __restrict__ targets,
                                                       float* __restrict__ G,
                                                       float* __restrict__ accum) {
  int bp = blockIdx.x;   // 0..15
  int t = blockIdx.y;    // 0..999
  int tid = threadIdx.x;
  int wave = tid >> 6, lane = tid & 63;
  size_t r1 = (size_t)bp * Tlen + t;
  size_t r2 = r1 + (size_t)16 * Tlen;
  const u16* z1 = Z + r1 * Vdim;
  const u16* z2 = Z + r2 * Vdim;

  __shared__ float ls1[Vdim];
  __shared__ float ls2[Vdim];
  __shared__ float red[8];

  float v1[8], v2[8];
  float mx1 = NEG, mx2 = NEG;
  #pragma unroll
  for (int i = 0; i < 8; ++i) {
    int col = i * 256 + tid;
    if (col < Vdim) {
      float bb = bias[col];
      v1[i] = bf2f(z1[col]) + bb;
      v2[i] = bf2f(z2[col]) + bb;
      ls1[col] = v1[i];
      ls2[col] = v2[i];
      mx1 = fmaxf(mx1, v1[i]);
      mx2 = fmaxf(mx2, v2[i]);
    } else { v1[i] = NEG; v2[i] = NEG; }
  }
  float w1 = waveMax(mx1), w2 = waveMax(mx2);
  if (lane == 0) { red[wave] = w1; red[4 + wave] = w2; }
  __syncthreads();
  float M1 = fmaxf(fmaxf(red[0], red[1]), fmaxf(red[2], red[3]));
  float M2 = fmaxf(fmaxf(red[4], red[5]), fmaxf(red[6], red[7]));
  __syncthreads();
  float s1 = 0.0f, s2 = 0.0f;
  #pragma unroll
  for (int i = 0; i < 8; ++i) {
    s1 += expf(v1[i] - M1);
    s2 += expf(v2[i] - M2);
  }
  s1 = waveSum(s1); s2 = waveSum(s2);
  if (lane == 0) { red[wave] = s1; red[4 + wave] = s2; }
  __syncthreads();
  float c1 = M1 + logf(red[0] + red[1] + red[2] + red[3]);
  float c2 = M2 + logf(red[4] + red[5] + red[6] + red[7]);

  if (tid < GROW) {
    float* G1 = G + r1 * GROW;
    float* G2 = G + r2 * GROW;
    float g1, g2;
    if (tid < Udim) {
      int i1 = targets[bp * Udim + tid];
      int i2 = targets[(bp + 16) * Udim + tid];
      g1 = (ls1[i1] - c1) * INVLN2;
      g2 = (ls2[i2] - c2) * INVLN2;
    } else if (tid == Udim) {
      g1 = (ls1[0] - c1) * INVLN2;   // blank
      g2 = (ls2[0] - c2) * INVLN2;
    } else {
      g1 = 0.0f; g2 = 0.0f;
    }
    G1[tid] = g1;
    G2[tid] = g2;
  }

  float f = 0.0f;
  #pragma unroll
  for (int i = 0; i < 8; ++i) {
    int col = i * 256 + tid;
    if (col < Vdim) {
      float p1 = expf(v1[i] - c1);
      float p2 = expf(v2[i] - c2);
      f += (p1 - p2) * (v1[i] - v2[i]);
    }
  }
  __syncthreads();
  f = waveSum(f);
  if (lane == 0) red[wave] = f;
  __syncthreads();
  if (tid == 0 && t < lens[bp]) {
    atomicAdd(&accum[1], 0.5f * (red[0] + red[1] + red[2] + red[3]));
  }
}

// ---------------- K4: CTC forward scan, one wave per sequence --------------
// 16-deep software pipeline in NAMED scalar registers (no arrays -> no
// scratch demotion). DPP wave_shr:1 for the lane-1 neighbor. Uniform
// predicated commit handles the tail; iteration count padded to x16.
#define PFD 16

#define DECL_SLOT(i) float s##i##x, s##i##y, s##i##b;
#define PRIME(i) { const float* r = gb + (size_t)(1 + i) * GROW;              \
    float2 v = *(const float2*)(r + 2 * lane);                                \
    s##i##x = v.x; s##i##y = v.y; s##i##b = r[Udim]; }
#define STEP(i) {                                                             \
    float lp1 = s##i##x, lp3 = s##i##y, lpBk = s##i##b;                       \
    int tp = t + (i) + PFD; tp = (tp < Tlen) ? tp : (Tlen - 1);               \
    const float* r = gb + (size_t)tp * GROW;                                  \
    float2 v = *(const float2*)(r + 2 * lane);                                \
    float nb = r[Udim];                                                       \
    float p3 = shiftup1(a3, NEG);                                             \
    float n0 = lse2_2(a0, p3) + lpBk;                                         \
    float n1 = lse3_2(a1, a0, skip1 ? p3 : NEG) + lp1;                        \
    float n2 = lse2_2(a2, a1) + lpBk;                                         \
    float n3 = lse3_2(a3, a2, skip3 ? a1 : NEG) + lp3;                        \
    bool act = (t + (i)) < len;                                               \
    a0 = act ? n0 : a0; a1 = act ? n1 : a1;                                   \
    a2 = act ? n2 : a2; a3 = act ? n3 : a3;                                   \
    s##i##x = v.x; s##i##y = v.y; s##i##b = nb; }

__global__ __launch_bounds__(64) void ctc_kernel(const float* __restrict__ G,
                                                 const int* __restrict__ targets,
                                                 const int* __restrict__ lens,
                                                 const int* __restrict__ tlens,
                                                 float* __restrict__ accum) {
  int b = blockIdx.x;
  int lane = threadIdx.x;
  const int* tgt = targets + b * Udim;
  int i1 = min(2 * lane, Udim - 1);
  int i3 = min(2 * lane + 1, Udim - 1);
  int l1 = tgt[i1];
  int l3 = tgt[i3];
  int lm1 = tgt[min(max(2 * lane - 1, 0), Udim - 1)];
  bool skip1 = (lane >= 1) && (l1 != lm1);
  bool skip3 = (l3 != l1);
  int len = lens[b];
  int tl = tlens[b];
  const float* gb = G + (size_t)b * Tlen * GROW;

  // t=0 init (log2 space)
  float a0 = (lane == 0) ? gb[Udim] : NEG;
  float a1 = (lane == 0) ? gb[0] : NEG;
  float a2 = NEG, a3 = NEG;

  DECL_SLOT(0)  DECL_SLOT(1)  DECL_SLOT(2)  DECL_SLOT(3)
  DECL_SLOT(4)  DECL_SLOT(5)  DECL_SLOT(6)  DECL_SLOT(7)
  DECL_SLOT(8)  DECL_SLOT(9)  DECL_SLOT(10) DECL_SLOT(11)
  DECL_SLOT(12) DECL_SLOT(13) DECL_SLOT(14) DECL_SLOT(15)

  PRIME(0)  PRIME(1)  PRIME(2)  PRIME(3)
  PRIME(4)  PRIME(5)  PRIME(6)  PRIME(7)
  PRIME(8)  PRIME(9)  PRIME(10) PRIME(11)
  PRIME(12) PRIME(13) PRIME(14) PRIME(15)

  int iters = ((len - 1) + (PFD - 1)) & ~(PFD - 1);   // covers t=1..len-1
  int t = 1;
  for (int blk = 0; blk < iters; blk += PFD) {
    STEP(0)  STEP(1)  STEP(2)  STEP(3)
    STEP(4)  STEP(5)  STEP(6)  STEP(7)
    STEP(8)  STEP(9)  STEP(10) STEP(11)
    STEP(12) STEP(13) STEP(14) STEP(15)
    t += PFD;
  }

  __shared__ float fin[256];
  fin[4 * lane + 0] = a0;
  fin[4 * lane + 1] = a1;
  fin[4 * lane + 2] = a2;
  fin[4 * lane + 3] = a3;
  __syncthreads();
  if (lane == 0) {
    int end = 2 * tl;
    float x = fin[end], y = fin[end - 1];
    float m = fmaxf(x, y);
    float loss = -LN2 * (m + log2f(exp2f(x - m) + exp2f(y - m)));
    atomicAdd(&accum[0], 0.5f * loss);
  }
}

// ---------------- K5: finalize to FP32 output ------------------------------
__global__ void finalize_kernel(const float* __restrict__ accum, float* __restrict__ out) {
  if (threadIdx.x == 0) {
    out[0] = accum[0];
    out[1] = accum[1];
  }
}

extern "C" void kernel_launch(void* const* d_in, const int* in_sizes, int n_in,
                              void* d_out, int out_size, void* d_ws, size_t ws_size,
                              hipStream_t stream) {
  const float* enc = (const float*)d_in[0];
  const float* W = (const float*)d_in[1];
  const float* bias = (const float*)d_in[2];
  const int* lens = (const int*)d_in[3];
  const int* targets = (const int*)d_in[4];
  const int* tlens = (const int*)d_in[5];

  char* ws = (char*)d_ws;
  u16* a_bf = (u16*)(ws + WS_ABF);
  u16* w_bf = (u16*)(ws + WS_WBF);
  u16* Zb   = (u16*)(ws + WS_Z);
  float* Gp  = (float*)(ws + WS_G);   // aliases a_bf (dead after gemm)
  float* accum = (float*)(ws + WS_ACC);

  hipLaunchKernelGGL(convert_kernel, dim3(1024), dim3(256), 0, stream,
                     (const float4*)enc, (const float4*)W, (uint4*)a_bf, (uint4*)w_bf, accum);
  hipLaunchKernelGGL(gemm_kernel, dim3(16, 250), dim3(256), 0, stream,
                     a_bf, w_bf, Zb);
  hipLaunchKernelGGL(cr_stats_kernel, dim3(16, 1000), dim3(256), 0, stream,
                     Zb, bias, lens, targets, Gp, accum);
  hipLaunchKernelGGL(ctc_kernel, dim3(Bsz), dim3(64), 0, stream,
                     Gp, targets, lens, tlens, accum);
  hipLaunchKernelGGL(finalize_kernel, dim3(1), dim3(64), 0, stream,
                     accum, (float*)d_out);
}

// Round 6
// 598.273 us; speedup vs baseline: 1.0882x; 1.0882x over previous
//
#include <hip/hip_runtime.h>
#include <hip/hip_bf16.h>
#include <cstdint>

#define NEG (-1.0e30f)
#define INVLN2 1.44269504088896340736f
#define LN2    0.69314718055994530942f

typedef unsigned short u16;
typedef __attribute__((ext_vector_type(8))) short short8;
typedef __attribute__((ext_vector_type(4))) float f32x4;

typedef const __attribute__((address_space(1))) void cg_void;
typedef __attribute__((address_space(3))) void lds_void;

// dims
#define Bsz   32
#define Tlen  1000
#define Cdim  512
#define Vdim  2000
#define Udim  100
#define Mrows (Bsz * Tlen)   // 32000
#define Npad  2048
#define GROW  128            // padded G row (floats): 0..99 labels, 100 blank, pad

// ws layout (bytes). G (16.4 MB) aliases a_bf (32.8 MB): a_bf dead after gemm.
#define WS_ABF 0u
#define WS_G   0u
#define WS_WBF 32768000u                    // a_bf: 32000*512*2
#define WS_Z   (WS_WBF + 2097152u)          // w_bf: 2048*512*2
#define WS_ACC (WS_Z + 128000000u)          // Z: 32000*2000*2; then accum: 2 floats

__device__ inline u16 f2bf(float x) {
  uint32_t u = __float_as_uint(x);
  uint32_t r = (u + 0x7fffu + ((u >> 16) & 1u)) >> 16;
  return (u16)r;
}
__device__ inline float bf2f(u16 u) {
  return __uint_as_float(((uint32_t)u) << 16);
}

__device__ inline float waveMax(float v) {
  #pragma unroll
  for (int o = 32; o > 0; o >>= 1) v = fmaxf(v, __shfl_down(v, o));
  return v;
}
__device__ inline float waveSum(float v) {
  #pragma unroll
  for (int o = 32; o > 0; o >>= 1) v += __shfl_down(v, o);
  return v;
}

// log-sum-exp in log2 space, minimized transcendental count.
// lse2: 1 exp2 + 1 log2.  lse3 (via med3/min3): 2 exp2 + 1 log2.
__device__ inline float lse2_2(float a, float b) {
  float m = fmaxf(a, b);
  float d = fminf(a, b) - m;             // <= 0
  return m + log2f(1.0f + exp2f(d));
}
__device__ inline float lse3_2(float a, float b, float c) {
  float m = fmaxf(a, fmaxf(b, c));
  float x = __builtin_amdgcn_fmed3f(a, b, c) - m;   // med - max <= 0
  float y = fminf(a, fminf(b, c)) - m;              // min - max <= 0
  return m + log2f(1.0f + exp2f(x) + exp2f(y));
}

// shift value from lane-1 into this lane via DPP wave_shr:1 (VALU, no LDS).
__device__ inline float shiftup1(float x, float fill) {
  int r = __builtin_amdgcn_update_dpp(__float_as_int(fill), __float_as_int(x),
                                      0x138, 0xF, 0xF, false);
  return __int_as_float(r);
}

// ---------------- K1: fp32 -> bf16 conversion, vectorized ------------------
__global__ void convert_kernel(const float4* __restrict__ enc4, const float4* __restrict__ W4,
                               uint4* __restrict__ a4, uint4* __restrict__ w4,
                               float* __restrict__ accum) {
  int idx = blockIdx.x * blockDim.x + threadIdx.x;
  int stride = gridDim.x * blockDim.x;
  if (idx == 0) { accum[0] = 0.0f; accum[1] = 0.0f; }
  const int nA = Mrows * Cdim / 8;
  const int nW = Vdim * Cdim / 8;
  const int nWp = Npad * Cdim / 8;
  for (int i = idx; i < nA; i += stride) {
    float4 x = enc4[2 * i], y = enc4[2 * i + 1];
    uint4 o;
    o.x = (uint32_t)f2bf(x.x) | ((uint32_t)f2bf(x.y) << 16);
    o.y = (uint32_t)f2bf(x.z) | ((uint32_t)f2bf(x.w) << 16);
    o.z = (uint32_t)f2bf(y.x) | ((uint32_t)f2bf(y.y) << 16);
    o.w = (uint32_t)f2bf(y.z) | ((uint32_t)f2bf(y.w) << 16);
    a4[i] = o;
  }
  for (int i = idx; i < nWp; i += stride) {
    uint4 o = {0, 0, 0, 0};
    if (i < nW) {
      float4 x = W4[2 * i], y = W4[2 * i + 1];
      o.x = (uint32_t)f2bf(x.x) | ((uint32_t)f2bf(x.y) << 16);
      o.y = (uint32_t)f2bf(x.z) | ((uint32_t)f2bf(x.w) << 16);
      o.z = (uint32_t)f2bf(y.x) | ((uint32_t)f2bf(y.y) << 16);
      o.w = (uint32_t)f2bf(y.z) | ((uint32_t)f2bf(y.w) << 16);
    }
    w4[i] = o;
  }
}

// ---------------- K2: bf16 GEMM (A: 32000x512, W: 2048x512, C = A*W^T) -----
__global__ __launch_bounds__(256) void gemm_kernel(const u16* __restrict__ A,
                                                   const u16* __restrict__ Wb,
                                                   u16* __restrict__ Z) {
  __shared__ __attribute__((aligned(16))) u16 As[128 * 64];
  __shared__ __attribute__((aligned(16))) u16 Bs[128 * 64];
  const int tid = threadIdx.x;
  const int wave = tid >> 6;
  const int lane = tid & 63;
  const int nBase = blockIdx.x * 128;
  const int mBase = blockIdx.y * 128;
  const int m_lane = lane & 15;
  const int quad = lane >> 4;

  f32x4 acc[4][4];
  const f32x4 zero4 = {0.0f, 0.0f, 0.0f, 0.0f};
  #pragma unroll
  for (int i = 0; i < 4; ++i)
    #pragma unroll
    for (int j = 0; j < 4; ++j) acc[i][j] = zero4;

  for (int k0 = 0; k0 < Cdim; k0 += 64) {
    #pragma unroll
    for (int r = 0; r < 4; ++r) {
      int u = r * 256 + tid;
      int g = u >> 3;
      int q = (u & 7) ^ (g & 7);
      const u16* gpA = A + ((size_t)(mBase + g) << 9) + (k0 + (q << 3));
      __builtin_amdgcn_global_load_lds((cg_void*)gpA, (lds_void*)&As[(r * 4 + wave) * 512],
                                       16, 0, 0);
      const u16* gpB = Wb + ((size_t)(nBase + g) << 9) + (k0 + (q << 3));
      __builtin_amdgcn_global_load_lds((cg_void*)gpB, (lds_void*)&Bs[(r * 4 + wave) * 512],
                                       16, 0, 0);
    }
    __syncthreads();
    #pragma unroll
    for (int kk = 0; kk < 2; ++kk) {
      short8 af[4], bfv[4];
      #pragma unroll
      for (int mi = 0; mi < 4; ++mi) {
        int row = (wave >> 1) * 64 + mi * 16 + m_lane;
        int q = (kk * 4 + quad) ^ (row & 7);
        af[mi] = *(const short8*)&As[row * 64 + (q << 3)];
      }
      #pragma unroll
      for (int ni = 0; ni < 4; ++ni) {
        int col = (wave & 1) * 64 + ni * 16 + m_lane;
        int q = (kk * 4 + quad) ^ (col & 7);
        bfv[ni] = *(const short8*)&Bs[col * 64 + (q << 3)];
      }
      #pragma unroll
      for (int mi = 0; mi < 4; ++mi)
        #pragma unroll
        for (int ni = 0; ni < 4; ++ni)
          acc[mi][ni] = __builtin_amdgcn_mfma_f32_16x16x32_bf16(af[mi], bfv[ni],
                                                                acc[mi][ni], 0, 0, 0);
    }
    __syncthreads();
  }
  #pragma unroll
  for (int ni = 0; ni < 4; ++ni) {
    int col = nBase + (wave & 1) * 64 + ni * 16 + m_lane;
    if (col < Vdim) {
      #pragma unroll
      for (int mi = 0; mi < 4; ++mi) {
        int row0 = mBase + (wave >> 1) * 64 + mi * 16 + quad * 4;
        #pragma unroll
        for (int rg = 0; rg < 4; ++rg)
          Z[(size_t)(row0 + rg) * Vdim + col] = f2bf(acc[mi][ni][rg]);
      }
    }
  }
}

// ---------------- K3: fused softmax stats + CR loss + CTC gather -----------
__global__ __launch_bounds__(256) void cr_stats_kernel(const u16* __restrict__ Z,
                                                       const float* __restrict__ bias,
                                                       const int* __restrict__ lens,
                                                       const int* __restrict__ targets,
                                                       float* __restrict__ G,
                                                       float* __restrict__ accum) {
  int bp = blockIdx.x;   // 0..15
  int t = blockIdx.y;    // 0..999
  int tid = threadIdx.x;
  int wave = tid >> 6, lane = tid & 63;
  size_t r1 = (size_t)bp * Tlen + t;
  size_t r2 = r1 + (size_t)16 * Tlen;
  const u16* z1 = Z + r1 * Vdim;
  const u16* z2 = Z + r2 * Vdim;

  __shared__ float ls1[Vdim];
  __shared__ float ls2[Vdim];
  __shared__ float red[8];

  float v1[8], v2[8];
  float mx1 = NEG, mx2 = NEG;
  #pragma unroll
  for (int i = 0; i < 8; ++i) {
    int col = i * 256 + tid;
    if (col < Vdim) {
      float bb = bias[col];
      v1[i] = bf2f(z1[col]) + bb;
      v2[i] = bf2f(z2[col]) + bb;
      ls1[col] = v1[i];
      ls2[col] = v2[i];
      mx1 = fmaxf(mx1, v1[i]);
      mx2 = fmaxf(mx2, v2[i]);
    } else { v1[i] = NEG; v2[i] = NEG; }
  }
  float w1 = waveMax(mx1), w2 = waveMax(mx2);
  if (lane == 0) { red[wave] = w1; red[4 + wave] = w2; }
  __syncthreads();
  float M1 = fmaxf(fmaxf(red[0], red[1]), fmaxf(red[2], red[3]));
  float M2 = fmaxf(fmaxf(red[4], red[5]), fmaxf(red[6], red[7]));
  __syncthreads();
  float s1 = 0.0f, s2 = 0.0f;
  #pragma unroll
  for (int i = 0; i < 8; ++i) {
    s1 += expf(v1[i] - M1);
    s2 += expf(v2[i] - M2);
  }
  s1 = waveSum(s1); s2 = waveSum(s2);
  if (lane == 0) { red[wave] = s1; red[4 + wave] = s2; }
  __syncthreads();
  float c1 = M1 + logf(red[0] + red[1] + red[2] + red[3]);
  float c2 = M2 + logf(red[4] + red[5] + red[6] + red[7]);

  if (tid < GROW) {
    float* G1 = G + r1 * GROW;
    float* G2 = G + r2 * GROW;
    float g1, g2;
    if (tid < Udim) {
      int i1 = targets[bp * Udim + tid];
      int i2 = targets[(bp + 16) * Udim + tid];
      g1 = (ls1[i1] - c1) * INVLN2;
      g2 = (ls2[i2] - c2) * INVLN2;
    } else if (tid == Udim) {
      g1 = (ls1[0] - c1) * INVLN2;   // blank
      g2 = (ls2[0] - c2) * INVLN2;
    } else {
      g1 = 0.0f; g2 = 0.0f;
    }
    G1[tid] = g1;
    G2[tid] = g2;
  }

  float f = 0.0f;
  #pragma unroll
  for (int i = 0; i < 8; ++i) {
    int col = i * 256 + tid;
    if (col < Vdim) {
      float p1 = expf(v1[i] - c1);
      float p2 = expf(v2[i] - c2);
      f += (p1 - p2) * (v1[i] - v2[i]);
    }
  }
  __syncthreads();
  f = waveSum(f);
  if (lane == 0) red[wave] = f;
  __syncthreads();
  if (tid == 0 && t < lens[bp]) {
    atomicAdd(&accum[1], 0.5f * (red[0] + red[1] + red[2] + red[3]));
  }
}

// ---------------- K4: CTC forward scan, one wave per sequence --------------
// 16-deep software pipeline, two NAMED register banks: block issues all 16
// refill loads (n-bank) before any compute, computes consume the s-bank,
// then s<-n. __launch_bounds__(64,1) raises the VGPR budget (~512) so the
// scheduler has no pressure incentive to sink loads to uses.
#define PFD 16

#define DECL_S(i) float s##i##x, s##i##y, s##i##b;
#define DECL_N(i) float n##i##x, n##i##y, n##i##b;
#define PRIME(i) { const float* r = gb + (size_t)(1 + i) * GROW;              \
    float2 v = *(const float2*)(r + 2 * lane);                                \
    s##i##x = v.x; s##i##y = v.y; s##i##b = r[Udim]; }
#define LOADN(i) { int tp = t + (i) + PFD; tp = (tp < Tlen) ? tp : (Tlen - 1);\
    const float* r = gb + (size_t)tp * GROW;                                  \
    float2 v = *(const float2*)(r + 2 * lane);                                \
    n##i##x = v.x; n##i##y = v.y; n##i##b = r[Udim]; }
#define COMP(i) {                                                             \
    float lp1 = s##i##x, lp3 = s##i##y, lpBk = s##i##b;                       \
    float p3 = shiftup1(a3, NEG);                                             \
    float n0 = lse2_2(a0, p3) + lpBk;                                         \
    float n1 = lse3_2(a1, a0, skip1 ? p3 : NEG) + lp1;                        \
    float n2 = lse2_2(a2, a1) + lpBk;                                         \
    float n3 = lse3_2(a3, a2, skip3 ? a1 : NEG) + lp3;                        \
    bool act = (t + (i)) < len;                                               \
    a0 = act ? n0 : a0; a1 = act ? n1 : a1;                                   \
    a2 = act ? n2 : a2; a3 = act ? n3 : a3;                                   \
    s##i##x = n##i##x; s##i##y = n##i##y; s##i##b = n##i##b; }

__global__ __launch_bounds__(64, 1) void ctc_kernel(const float* __restrict__ G,
                                                    const int* __restrict__ targets,
                                                    const int* __restrict__ lens,
                                                    const int* __restrict__ tlens,
                                                    float* __restrict__ accum) {
  int b = blockIdx.x;
  int lane = threadIdx.x;
  const int* tgt = targets + b * Udim;
  int i1 = min(2 * lane, Udim - 1);
  int i3 = min(2 * lane + 1, Udim - 1);
  int l1 = tgt[i1];
  int l3 = tgt[i3];
  int lm1 = tgt[min(max(2 * lane - 1, 0), Udim - 1)];
  bool skip1 = (lane >= 1) && (l1 != lm1);
  bool skip3 = (l3 != l1);
  int len = lens[b];
  int tl = tlens[b];
  const float* gb = G + (size_t)b * Tlen * GROW;

  // t=0 init (log2 space)
  float a0 = (lane == 0) ? gb[Udim] : NEG;
  float a1 = (lane == 0) ? gb[0] : NEG;
  float a2 = NEG, a3 = NEG;

  DECL_S(0)  DECL_S(1)  DECL_S(2)  DECL_S(3)
  DECL_S(4)  DECL_S(5)  DECL_S(6)  DECL_S(7)
  DECL_S(8)  DECL_S(9)  DECL_S(10) DECL_S(11)
  DECL_S(12) DECL_S(13) DECL_S(14) DECL_S(15)
  DECL_N(0)  DECL_N(1)  DECL_N(2)  DECL_N(3)
  DECL_N(4)  DECL_N(5)  DECL_N(6)  DECL_N(7)
  DECL_N(8)  DECL_N(9)  DECL_N(10) DECL_N(11)
  DECL_N(12) DECL_N(13) DECL_N(14) DECL_N(15)

  PRIME(0)  PRIME(1)  PRIME(2)  PRIME(3)
  PRIME(4)  PRIME(5)  PRIME(6)  PRIME(7)
  PRIME(8)  PRIME(9)  PRIME(10) PRIME(11)
  PRIME(12) PRIME(13) PRIME(14) PRIME(15)

  int iters = ((len - 1) + (PFD - 1)) & ~(PFD - 1);   // covers t=1..len-1
  int t = 1;
  for (int blk = 0; blk < iters; blk += PFD) {
    // issue ALL refill loads first (independent of the recurrence chain)
    LOADN(0)  LOADN(1)  LOADN(2)  LOADN(3)
    LOADN(4)  LOADN(5)  LOADN(6)  LOADN(7)
    LOADN(8)  LOADN(9)  LOADN(10) LOADN(11)
    LOADN(12) LOADN(13) LOADN(14) LOADN(15)
    // then run the recurrence on the s-bank
    COMP(0)  COMP(1)  COMP(2)  COMP(3)
    COMP(4)  COMP(5)  COMP(6)  COMP(7)
    COMP(8)  COMP(9)  COMP(10) COMP(11)
    COMP(12) COMP(13) COMP(14) COMP(15)
    t += PFD;
  }

  __shared__ float fin[256];
  fin[4 * lane + 0] = a0;
  fin[4 * lane + 1] = a1;
  fin[4 * lane + 2] = a2;
  fin[4 * lane + 3] = a3;
  __syncthreads();
  if (lane == 0) {
    int end = 2 * tl;
    float x = fin[end], y = fin[end - 1];
    float m = fmaxf(x, y);
    float loss = -LN2 * (m + log2f(exp2f(x - m) + exp2f(y - m)));
    atomicAdd(&accum[0], 0.5f * loss);
  }
}

// ---------------- K5: finalize to FP32 output ------------------------------
__global__ void finalize_kernel(const float* __restrict__ accum, float* __restrict__ out) {
  if (threadIdx.x == 0) {
    out[0] = accum[0];
    out[1] = accum[1];
  }
}

extern "C" void kernel_launch(void* const* d_in, const int* in_sizes, int n_in,
                              void* d_out, int out_size, void* d_ws, size_t ws_size,
                              hipStream_t stream) {
  const float* enc = (const float*)d_in[0];
  const float* W = (const float*)d_in[1];
  const float* bias = (const float*)d_in[2];
  const int* lens = (const int*)d_in[3];
  const int* targets = (const int*)d_in[4];
  const int* tlens = (const int*)d_in[5];

  char* ws = (char*)d_ws;
  u16* a_bf = (u16*)(ws + WS_ABF);
  u16* w_bf = (u16*)(ws + WS_WBF);
  u16* Zb   = (u16*)(ws + WS_Z);
  float* Gp  = (float*)(ws + WS_G);   // aliases a_bf (dead after gemm)
  float* accum = (float*)(ws + WS_ACC);

  hipLaunchKernelGGL(convert_kernel, dim3(1024), dim3(256), 0, stream,
                     (const float4*)enc, (const float4*)W, (uint4*)a_bf, (uint4*)w_bf, accum);
  hipLaunchKernelGGL(gemm_kernel, dim3(16, 250), dim3(256), 0, stream,
                     a_bf, w_bf, Zb);
  hipLaunchKernelGGL(cr_stats_kernel, dim3(16, 1000), dim3(256), 0, stream,
                     Zb, bias, lens, targets, Gp, accum);
  hipLaunchKernelGGL(ctc_kernel, dim3(Bsz), dim3(64), 0, stream,
                     Gp, targets, lens, tlens, accum);
  hipLaunchKernelGGL(finalize_kernel, dim3(1), dim3(64), 0, stream,
                     accum, (float*)d_out);
}

// Round 7
// 592.033 us; speedup vs baseline: 1.0997x; 1.0105x over previous
//
#include <hip/hip_runtime.h>
#include <hip/hip_bf16.h>
#include <cstdint>

#define NEG (-1.0e30f)
#define INVLN2 1.44269504088896340736f
#define LN2    0.69314718055994530942f

typedef unsigned short u16;
typedef __attribute__((ext_vector_type(8))) short short8;
typedef __attribute__((ext_vector_type(4))) float f32x4;

typedef const __attribute__((address_space(1))) void cg_void;
typedef __attribute__((address_space(3))) void lds_void;

// dims
#define Bsz   32
#define Tlen  1000
#define Cdim  512
#define Vdim  2000
#define Udim  100
#define Mrows (Bsz * Tlen)   // 32000
#define Npad  2048
#define GROW  256            // G row stride in floats (1024 B): lane i owns
                             // float4 {lp(tgt[2i]), lp(tgt[2i+1]), lp(blank), 0}

// ws layout (bytes). G (32.768 MB) aliases a_bf exactly (dead after gemm).
#define WS_ABF 0u
#define WS_G   0u
#define WS_WBF 32768000u                    // a_bf/G: 32000*1024
#define WS_Z   (WS_WBF + 2097152u)          // w_bf: 2048*512*2
#define WS_ACC (WS_Z + 128000000u)          // Z: 32000*2000*2; then accum: 2 floats

__device__ inline u16 f2bf(float x) {
  uint32_t u = __float_as_uint(x);
  uint32_t r = (u + 0x7fffu + ((u >> 16) & 1u)) >> 16;
  return (u16)r;
}
__device__ inline float bf2f(u16 u) {
  return __uint_as_float(((uint32_t)u) << 16);
}

__device__ inline float waveMax(float v) {
  #pragma unroll
  for (int o = 32; o > 0; o >>= 1) v = fmaxf(v, __shfl_down(v, o));
  return v;
}
__device__ inline float waveSum(float v) {
  #pragma unroll
  for (int o = 32; o > 0; o >>= 1) v += __shfl_down(v, o);
  return v;
}

// log-sum-exp in log2 space, minimized transcendental count.
__device__ inline float lse2_2(float a, float b) {
  float m = fmaxf(a, b);
  float d = fminf(a, b) - m;
  return m + log2f(1.0f + exp2f(d));
}
__device__ inline float lse3_2(float a, float b, float c) {
  float m = fmaxf(a, fmaxf(b, c));
  float x = __builtin_amdgcn_fmed3f(a, b, c) - m;
  float y = fminf(a, fminf(b, c)) - m;
  return m + log2f(1.0f + exp2f(x) + exp2f(y));
}

// shift value from lane-1 into this lane via DPP wave_shr:1 (VALU, no LDS).
__device__ inline float shiftup1(float x, float fill) {
  int r = __builtin_amdgcn_update_dpp(__float_as_int(fill), __float_as_int(x),
                                      0x138, 0xF, 0xF, false);
  return __int_as_float(r);
}

// ---------------- K1: fp32 -> bf16 conversion, vectorized ------------------
__global__ void convert_kernel(const float4* __restrict__ enc4, const float4* __restrict__ W4,
                               uint4* __restrict__ a4, uint4* __restrict__ w4,
                               float* __restrict__ accum) {
  int idx = blockIdx.x * blockDim.x + threadIdx.x;
  int stride = gridDim.x * blockDim.x;
  if (idx == 0) { accum[0] = 0.0f; accum[1] = 0.0f; }
  const int nA = Mrows * Cdim / 8;
  const int nW = Vdim * Cdim / 8;
  const int nWp = Npad * Cdim / 8;
  for (int i = idx; i < nA; i += stride) {
    float4 x = enc4[2 * i], y = enc4[2 * i + 1];
    uint4 o;
    o.x = (uint32_t)f2bf(x.x) | ((uint32_t)f2bf(x.y) << 16);
    o.y = (uint32_t)f2bf(x.z) | ((uint32_t)f2bf(x.w) << 16);
    o.z = (uint32_t)f2bf(y.x) | ((uint32_t)f2bf(y.y) << 16);
    o.w = (uint32_t)f2bf(y.z) | ((uint32_t)f2bf(y.w) << 16);
    a4[i] = o;
  }
  for (int i = idx; i < nWp; i += stride) {
    uint4 o = {0, 0, 0, 0};
    if (i < nW) {
      float4 x = W4[2 * i], y = W4[2 * i + 1];
      o.x = (uint32_t)f2bf(x.x) | ((uint32_t)f2bf(x.y) << 16);
      o.y = (uint32_t)f2bf(x.z) | ((uint32_t)f2bf(x.w) << 16);
      o.z = (uint32_t)f2bf(y.x) | ((uint32_t)f2bf(y.y) << 16);
      o.w = (uint32_t)f2bf(y.z) | ((uint32_t)f2bf(y.w) << 16);
    }
    w4[i] = o;
  }
}

// ---------------- K2: bf16 GEMM (A: 32000x512, W: 2048x512, C = A*W^T) -----
__global__ __launch_bounds__(256) void gemm_kernel(const u16* __restrict__ A,
                                                   const u16* __restrict__ Wb,
                                                   u16* __restrict__ Z) {
  __shared__ __attribute__((aligned(16))) u16 As[128 * 64];
  __shared__ __attribute__((aligned(16))) u16 Bs[128 * 64];
  const int tid = threadIdx.x;
  const int wave = tid >> 6;
  const int lane = tid & 63;
  const int nBase = blockIdx.x * 128;
  const int mBase = blockIdx.y * 128;
  const int m_lane = lane & 15;
  const int quad = lane >> 4;

  f32x4 acc[4][4];
  const f32x4 zero4 = {0.0f, 0.0f, 0.0f, 0.0f};
  #pragma unroll
  for (int i = 0; i < 4; ++i)
    #pragma unroll
    for (int j = 0; j < 4; ++j) acc[i][j] = zero4;

  for (int k0 = 0; k0 < Cdim; k0 += 64) {
    #pragma unroll
    for (int r = 0; r < 4; ++r) {
      int u = r * 256 + tid;
      int g = u >> 3;
      int q = (u & 7) ^ (g & 7);
      const u16* gpA = A + ((size_t)(mBase + g) << 9) + (k0 + (q << 3));
      __builtin_amdgcn_global_load_lds((cg_void*)gpA, (lds_void*)&As[(r * 4 + wave) * 512],
                                       16, 0, 0);
      const u16* gpB = Wb + ((size_t)(nBase + g) << 9) + (k0 + (q << 3));
      __builtin_amdgcn_global_load_lds((cg_void*)gpB, (lds_void*)&Bs[(r * 4 + wave) * 512],
                                       16, 0, 0);
    }
    __syncthreads();
    #pragma unroll
    for (int kk = 0; kk < 2; ++kk) {
      short8 af[4], bfv[4];
      #pragma unroll
      for (int mi = 0; mi < 4; ++mi) {
        int row = (wave >> 1) * 64 + mi * 16 + m_lane;
        int q = (kk * 4 + quad) ^ (row & 7);
        af[mi] = *(const short8*)&As[row * 64 + (q << 3)];
      }
      #pragma unroll
      for (int ni = 0; ni < 4; ++ni) {
        int col = (wave & 1) * 64 + ni * 16 + m_lane;
        int q = (kk * 4 + quad) ^ (col & 7);
        bfv[ni] = *(const short8*)&Bs[col * 64 + (q << 3)];
      }
      #pragma unroll
      for (int mi = 0; mi < 4; ++mi)
        #pragma unroll
        for (int ni = 0; ni < 4; ++ni)
          acc[mi][ni] = __builtin_amdgcn_mfma_f32_16x16x32_bf16(af[mi], bfv[ni],
                                                                acc[mi][ni], 0, 0, 0);
    }
    __syncthreads();
  }
  #pragma unroll
  for (int ni = 0; ni < 4; ++ni) {
    int col = nBase + (wave & 1) * 64 + ni * 16 + m_lane;
    if (col < Vdim) {
      #pragma unroll
      for (int mi = 0; mi < 4; ++mi) {
        int row0 = mBase + (wave >> 1) * 64 + mi * 16 + quad * 4;
        #pragma unroll
        for (int rg = 0; rg < 4; ++rg)
          Z[(size_t)(row0 + rg) * Vdim + col] = f2bf(acc[mi][ni][rg]);
      }
    }
  }
}

// ---------------- K3: fused softmax stats + CR loss + CTC gather -----------
// Emits G rows of 64 float4s: lane i gets {lp(tgt[2i]), lp(tgt[2i+1]),
// lp(blank), 0} in log2 space (labels pre-clamped, blank replicated).
__global__ __launch_bounds__(256) void cr_stats_kernel(const u16* __restrict__ Z,
                                                       const float* __restrict__ bias,
                                                       const int* __restrict__ lens,
                                                       const int* __restrict__ targets,
                                                       float* __restrict__ G,
                                                       float* __restrict__ accum) {
  int bp = blockIdx.x;   // 0..15
  int t = blockIdx.y;    // 0..999
  int tid = threadIdx.x;
  int wave = tid >> 6, lane = tid & 63;
  size_t r1 = (size_t)bp * Tlen + t;
  size_t r2 = r1 + (size_t)16 * Tlen;
  const u16* z1 = Z + r1 * Vdim;
  const u16* z2 = Z + r2 * Vdim;

  __shared__ float ls1[Vdim];
  __shared__ float ls2[Vdim];
  __shared__ float red[8];

  float v1[8], v2[8];
  float mx1 = NEG, mx2 = NEG;
  #pragma unroll
  for (int i = 0; i < 8; ++i) {
    int col = i * 256 + tid;
    if (col < Vdim) {
      float bb = bias[col];
      v1[i] = bf2f(z1[col]) + bb;
      v2[i] = bf2f(z2[col]) + bb;
      ls1[col] = v1[i];
      ls2[col] = v2[i];
      mx1 = fmaxf(mx1, v1[i]);
      mx2 = fmaxf(mx2, v2[i]);
    } else { v1[i] = NEG; v2[i] = NEG; }
  }
  float w1 = waveMax(mx1), w2 = waveMax(mx2);
  if (lane == 0) { red[wave] = w1; red[4 + wave] = w2; }
  __syncthreads();
  float M1 = fmaxf(fmaxf(red[0], red[1]), fmaxf(red[2], red[3]));
  float M2 = fmaxf(fmaxf(red[4], red[5]), fmaxf(red[6], red[7]));
  __syncthreads();
  float s1 = 0.0f, s2 = 0.0f;
  #pragma unroll
  for (int i = 0; i < 8; ++i) {
    s1 += expf(v1[i] - M1);
    s2 += expf(v2[i] - M2);
  }
  s1 = waveSum(s1); s2 = waveSum(s2);
  if (lane == 0) { red[wave] = s1; red[4 + wave] = s2; }
  __syncthreads();
  float c1 = M1 + logf(red[0] + red[1] + red[2] + red[3]);
  float c2 = M2 + logf(red[4] + red[5] + red[6] + red[7]);

  if (tid < 64) {
    int i1 = min(2 * tid, Udim - 1);
    int i3 = min(2 * tid + 1, Udim - 1);
    int t1a = targets[bp * Udim + i1];
    int t1b = targets[bp * Udim + i3];
    int t2a = targets[(bp + 16) * Udim + i1];
    int t2b = targets[(bp + 16) * Udim + i3];
    float4 g1 = {(ls1[t1a] - c1) * INVLN2, (ls1[t1b] - c1) * INVLN2,
                 (ls1[0] - c1) * INVLN2, 0.0f};
    float4 g2 = {(ls2[t2a] - c2) * INVLN2, (ls2[t2b] - c2) * INVLN2,
                 (ls2[0] - c2) * INVLN2, 0.0f};
    *(float4*)(G + r1 * GROW + 4 * tid) = g1;
    *(float4*)(G + r2 * GROW + 4 * tid) = g2;
  }

  float f = 0.0f;
  #pragma unroll
  for (int i = 0; i < 8; ++i) {
    int col = i * 256 + tid;
    if (col < Vdim) {
      float p1 = expf(v1[i] - c1);
      float p2 = expf(v2[i] - c2);
      f += (p1 - p2) * (v1[i] - v2[i]);
    }
  }
  __syncthreads();
  f = waveSum(f);
  if (lane == 0) red[wave] = f;
  __syncthreads();
  if (tid == 0 && t < lens[bp]) {
    atomicAdd(&accum[1], 0.5f * (red[0] + red[1] + red[2] + red[3]));
  }
}

// ---------------- K4: CTC forward scan, one wave per sequence --------------
// 16-deep pipeline; ONE float4 load per step (blank replicated in .z).
// sched_barrier(0) fences the 16-load batch above the 16 recurrence steps so
// the machine scheduler cannot sink loads to their uses (rounds 3-6 failure
// mode: VGPR=28-32, loads collapsed to depth 1, ~590 cyc/iter).
#define PFD 16

#define DECL_S(i) float s##i##x, s##i##y, s##i##b;
#define DECL_N(i) float n##i##x, n##i##y, n##i##b;
#define PRIME(i) { float4 v = *(const float4*)(gb + (size_t)(1 + i) * GROW + 4 * lane); \
    s##i##x = v.x; s##i##y = v.y; s##i##b = v.z; }
#define LOADN(i) { int tp = t + (i) + PFD; tp = (tp < Tlen) ? tp : (Tlen - 1);\
    float4 v = *(const float4*)(gb + (size_t)tp * GROW + 4 * lane);           \
    n##i##x = v.x; n##i##y = v.y; n##i##b = v.z; }
#define COMP(i) {                                                             \
    float lp1 = s##i##x, lp3 = s##i##y, lpBk = s##i##b;                       \
    float p3 = shiftup1(a3, NEG);                                             \
    float n0 = lse2_2(a0, p3) + lpBk;                                         \
    float n1 = lse3_2(a1, a0, skip1 ? p3 : NEG) + lp1;                        \
    float n2 = lse2_2(a2, a1) + lpBk;                                         \
    float n3 = lse3_2(a3, a2, skip3 ? a1 : NEG) + lp3;                        \
    bool act = (t + (i)) < len;                                               \
    a0 = act ? n0 : a0; a1 = act ? n1 : a1;                                   \
    a2 = act ? n2 : a2; a3 = act ? n3 : a3;                                   \
    s##i##x = n##i##x; s##i##y = n##i##y; s##i##b = n##i##b; }

__global__ __launch_bounds__(64, 1) void ctc_kernel(const float* __restrict__ G,
                                                    const int* __restrict__ targets,
                                                    const int* __restrict__ lens,
                                                    const int* __restrict__ tlens,
                                                    float* __restrict__ accum) {
  int b = blockIdx.x;
  int lane = threadIdx.x;
  const int* tgt = targets + b * Udim;
  int i1 = min(2 * lane, Udim - 1);
  int i3 = min(2 * lane + 1, Udim - 1);
  int l1 = tgt[i1];
  int l3 = tgt[i3];
  int lm1 = tgt[min(max(2 * lane - 1, 0), Udim - 1)];
  bool skip1 = (lane >= 1) && (l1 != lm1);
  bool skip3 = (l3 != l1);
  int len = lens[b];
  int tl = tlens[b];
  const float* gb = G + (size_t)b * Tlen * GROW;

  // t=0 init (log2 space): lane0's float4 = {lp(tgt0), lp(tgt1), blank, 0}
  float4 v0 = *(const float4*)(gb + 4 * lane);
  float a0 = (lane == 0) ? v0.z : NEG;
  float a1 = (lane == 0) ? v0.x : NEG;
  float a2 = NEG, a3 = NEG;

  DECL_S(0)  DECL_S(1)  DECL_S(2)  DECL_S(3)
  DECL_S(4)  DECL_S(5)  DECL_S(6)  DECL_S(7)
  DECL_S(8)  DECL_S(9)  DECL_S(10) DECL_S(11)
  DECL_S(12) DECL_S(13) DECL_S(14) DECL_S(15)
  DECL_N(0)  DECL_N(1)  DECL_N(2)  DECL_N(3)
  DECL_N(4)  DECL_N(5)  DECL_N(6)  DECL_N(7)
  DECL_N(8)  DECL_N(9)  DECL_N(10) DECL_N(11)
  DECL_N(12) DECL_N(13) DECL_N(14) DECL_N(15)

  PRIME(0)  PRIME(1)  PRIME(2)  PRIME(3)
  PRIME(4)  PRIME(5)  PRIME(6)  PRIME(7)
  PRIME(8)  PRIME(9)  PRIME(10) PRIME(11)
  PRIME(12) PRIME(13) PRIME(14) PRIME(15)

  int iters = ((len - 1) + (PFD - 1)) & ~(PFD - 1);   // covers t=1..len-1
  int t = 1;
  for (int blk = 0; blk < iters; blk += PFD) {
    // batch-issue all 16 refill loads...
    LOADN(0)  LOADN(1)  LOADN(2)  LOADN(3)
    LOADN(4)  LOADN(5)  LOADN(6)  LOADN(7)
    LOADN(8)  LOADN(9)  LOADN(10) LOADN(11)
    LOADN(12) LOADN(13) LOADN(14) LOADN(15)
    // ...and FENCE: scheduler may not sink them past this point.
    __builtin_amdgcn_sched_barrier(0);
    COMP(0)  COMP(1)  COMP(2)  COMP(3)
    COMP(4)  COMP(5)  COMP(6)  COMP(7)
    COMP(8)  COMP(9)  COMP(10) COMP(11)
    COMP(12) COMP(13) COMP(14) COMP(15)
    t += PFD;
  }

  __shared__ float fin[256];
  fin[4 * lane + 0] = a0;
  fin[4 * lane + 1] = a1;
  fin[4 * lane + 2] = a2;
  fin[4 * lane + 3] = a3;
  __syncthreads();
  if (lane == 0) {
    int end = 2 * tl;
    float x = fin[end], y = fin[end - 1];
    float m = fmaxf(x, y);
    float loss = -LN2 * (m + log2f(exp2f(x - m) + exp2f(y - m)));
    atomicAdd(&accum[0], 0.5f * loss);
  }
}

// ---------------- K5: finalize to FP32 output ------------------------------
__global__ void finalize_kernel(const float* __restrict__ accum, float* __restrict__ out) {
  if (threadIdx.x == 0) {
    out[0] = accum[0];
    out[1] = accum[1];
  }
}

extern "C" void kernel_launch(void* const* d_in, const int* in_sizes, int n_in,
                              void* d_out, int out_size, void* d_ws, size_t ws_size,
                              hipStream_t stream) {
  const float* enc = (const float*)d_in[0];
  const float* W = (const float*)d_in[1];
  const float* bias = (const float*)d_in[2];
  const int* lens = (const int*)d_in[3];
  const int* targets = (const int*)d_in[4];
  const int* tlens = (const int*)d_in[5];

  char* ws = (char*)d_ws;
  u16* a_bf = (u16*)(ws + WS_ABF);
  u16* w_bf = (u16*)(ws + WS_WBF);
  u16* Zb   = (u16*)(ws + WS_Z);
  float* Gp  = (float*)(ws + WS_G);   // aliases a_bf (dead after gemm)
  float* accum = (float*)(ws + WS_ACC);

  hipLaunchKernelGGL(convert_kernel, dim3(1024), dim3(256), 0, stream,
                     (const float4*)enc, (const float4*)W, (uint4*)a_bf, (uint4*)w_bf, accum);
  hipLaunchKernelGGL(gemm_kernel, dim3(16, 250), dim3(256), 0, stream,
                     a_bf, w_bf, Zb);
  hipLaunchKernelGGL(cr_stats_kernel, dim3(16, 1000), dim3(256), 0, stream,
                     Zb, bias, lens, targets, Gp, accum);
  hipLaunchKernelGGL(ctc_kernel, dim3(Bsz), dim3(64), 0, stream,
                     Gp, targets, lens, tlens, accum);
  hipLaunchKernelGGL(finalize_kernel, dim3(1), dim3(64), 0, stream,
                     accum, (float*)d_out);
}